// Round 1
// baseline (1985.204 us; speedup 1.0000x reference)
//
#include <hip/hip_runtime.h>
#include <hip/hip_bf16.h>

#define B_ 2
#define S_ 2048
#define HID_ 4096
#define NH_ 32
#define NKV_ 8
#define HD_ 128
#define T_ (B_*S_)

typedef __bf16 bf16;
typedef __bf16 bf16x8 __attribute__((ext_vector_type(8)));
typedef __bf16 bf16x4 __attribute__((ext_vector_type(4)));
typedef float f32x4 __attribute__((ext_vector_type(4)));

// ---------------- convert fp32 -> bf16 ----------------
__global__ __launch_bounds__(256) void cvt_bf16_kernel(const float* __restrict__ in,
                                                       bf16* __restrict__ out, int n4) {
  int idx = blockIdx.x * 256 + threadIdx.x;
  if (idx >= n4) return;
  float4 v = ((const float4*)in)[idx];
  bf16x4 o;
  o.x = (bf16)v.x; o.y = (bf16)v.y; o.z = (bf16)v.z; o.w = (bf16)v.w;
  ((bf16x4*)out)[idx] = o;
}

// ---------------- dequant int4(stored int32) -> bf16 ----------------
// w = (qw - 8) * scale[o][i/128]
__global__ __launch_bounds__(256) void dequant_kernel(const int* __restrict__ qw,
                                                      const float* __restrict__ scale,
                                                      bf16* __restrict__ out,
                                                      int OD, int ID) {
  int idx = blockIdx.x * 256 + threadIdx.x;
  int perRow = ID >> 3;                 // chunks of 8 per row (pow2)
  int total = OD * perRow;
  if (idx >= total) return;
  int o = idx / perRow;
  int ic = idx - o * perRow;            // chunk index
  float s = scale[o * (ID >> 7) + ((ic * 8) >> 7)];
  const int* q = qw + (size_t)o * ID + ic * 8;
  int4 q0 = *(const int4*)q;
  int4 q1 = *(const int4*)(q + 4);
  bf16x8 r;
  r[0] = (bf16)((q0.x - 8) * s);
  r[1] = (bf16)((q0.y - 8) * s);
  r[2] = (bf16)((q0.z - 8) * s);
  r[3] = (bf16)((q0.w - 8) * s);
  r[4] = (bf16)((q1.x - 8) * s);
  r[5] = (bf16)((q1.y - 8) * s);
  r[6] = (bf16)((q1.z - 8) * s);
  r[7] = (bf16)((q1.w - 8) * s);
  *(bf16x8*)(out + (size_t)o * ID + ic * 8) = r;
}

// ---------------- GEMM: C[M][N] = A[M][K] * B[N][K]^T ----------------
// 64x64 tile, BK=64, 256 threads (4 waves, each wave: 16 rows x 64 cols)
// LDS fragment-order layout: element [row][k] at chunk (k/8)*64 + row, slot k%8
__global__ __launch_bounds__(256) void gemm_bt_kernel(const bf16* __restrict__ A,
                                                      const bf16* __restrict__ Bm,
                                                      void* __restrict__ Cout,
                                                      int N, int K, int c_fp32) {
  __shared__ bf16 As[8 * 64 * 8];   // 8KB
  __shared__ bf16 Bs[8 * 64 * 8];   // 8KB
  int tid = threadIdx.x;
  int wave = tid >> 6, lane = tid & 63, quad = lane >> 4, l16 = lane & 15;
  int m0 = blockIdx.y * 64, n0 = blockIdx.x * 64;
  int srow = tid >> 2, sc = tid & 3;
  const bf16* Ap = A + (size_t)(m0 + srow) * K + sc * 8;
  const bf16* Bp = Bm + (size_t)(n0 + srow) * K + sc * 8;
  f32x4 acc[4];
#pragma unroll
  for (int nt = 0; nt < 4; nt++) acc[nt] = (f32x4){0.f, 0.f, 0.f, 0.f};

  for (int k0 = 0; k0 < K; k0 += 64) {
    __syncthreads();
    *(uint4*)&As[(sc * 64 + srow) * 8]       = *(const uint4*)(Ap + k0);
    *(uint4*)&As[((sc + 4) * 64 + srow) * 8] = *(const uint4*)(Ap + k0 + 32);
    *(uint4*)&Bs[(sc * 64 + srow) * 8]       = *(const uint4*)(Bp + k0);
    *(uint4*)&Bs[((sc + 4) * 64 + srow) * 8] = *(const uint4*)(Bp + k0 + 32);
    __syncthreads();
#pragma unroll
    for (int kk = 0; kk < 2; kk++) {
      bf16x8 a = *(bf16x8*)&As[((kk * 4 + quad) * 64 + wave * 16 + l16) * 8];
#pragma unroll
      for (int nt = 0; nt < 4; nt++) {
        bf16x8 b = *(bf16x8*)&Bs[((kk * 4 + quad) * 64 + nt * 16 + l16) * 8];
        acc[nt] = __builtin_amdgcn_mfma_f32_16x16x32_bf16(a, b, acc[nt], 0, 0, 0);
      }
    }
  }
#pragma unroll
  for (int nt = 0; nt < 4; nt++) {
#pragma unroll
    for (int r = 0; r < 4; r++) {
      int rr = m0 + wave * 16 + quad * 4 + r;
      int cc = n0 + nt * 16 + l16;
      if (c_fp32) ((float*)Cout)[(size_t)rr * N + cc] = acc[nt][r];
      else        ((bf16*)Cout)[(size_t)rr * N + cc] = (bf16)acc[nt][r];
    }
  }
}

// ---------------- RoPE (in place, on [T][nheads*128] bf16) ----------------
__global__ __launch_bounds__(256) void rope_kernel(bf16* __restrict__ X,
                                                   const float* __restrict__ cosT,
                                                   const float* __restrict__ sinT,
                                                   int nheads) {
  int idx = blockIdx.x * 256 + threadIdx.x;
  int total = T_ * nheads * 64;
  if (idx >= total) return;
  int d0 = idx & 63;
  int h = (idx >> 6) & (nheads - 1);       // nheads pow2 (32 or 8)
  int t = idx / (nheads * 64);
  size_t base = (size_t)t * (nheads * 128) + h * 128;
  float x1 = (float)X[base + d0];
  float x2 = (float)X[base + d0 + 64];
  float c1 = cosT[t * 128 + d0],      s1 = sinT[t * 128 + d0];
  float c2 = cosT[t * 128 + d0 + 64], s2 = sinT[t * 128 + d0 + 64];
  X[base + d0]      = (bf16)(x1 * c1 - x2 * s1);
  X[base + d0 + 64] = (bf16)(x2 * c2 + x1 * s2);
}

// ---------------- fused causal GQA attention (flash-style) ----------------
// grid: (S/64, NH, B); block 256 = 4 waves; wave owns 16 query rows
__global__ __launch_bounds__(256) void attn_kernel(const bf16* __restrict__ Qm,
                                                   const bf16* __restrict__ Km,
                                                   const bf16* __restrict__ Vm,
                                                   bf16* __restrict__ Cm) {
  __shared__ bf16 Ks[16 * 64 * 8];   // 16KB: chunk = dc*64 + key
  __shared__ bf16 Vt[8 * 128 * 8];   // 16KB: chunk = (key>>3)*128 + d, slot key&7
  __shared__ bf16 Ps[4 * 16 * 64];   // 8KB: per-wave P in A-frag layout
  int tid = threadIdx.x;
  int wave = tid >> 6, lane = tid & 63, quad = lane >> 4, l16 = lane & 15;
  int qt = blockIdx.x, h = blockIdx.y, b = blockIdx.z;
  int kvh = h >> 2;
  int q0 = qt * 64;
  const float scaling = 0.08838834764831845f;  // 1/sqrt(128)

  // Q fragments (loop-invariant): A[m=l16][k=quad*8+j], 4 K-steps of 32
  bf16x8 aQ[4];
  {
    size_t qbase = (size_t)(b * S_ + q0 + wave * 16 + l16) * (NH_ * HD_) + h * HD_;
#pragma unroll
    for (int kt = 0; kt < 4; kt++)
      aQ[kt] = *(const bf16x8*)(Qm + qbase + kt * 32 + quad * 8);
  }

  float mcur[4], lcur[4];
  f32x4 O[8];
#pragma unroll
  for (int r = 0; r < 4; r++) { mcur[r] = -1e30f; lcur[r] = 0.f; }
#pragma unroll
  for (int n = 0; n < 8; n++) O[n] = (f32x4){0.f, 0.f, 0.f, 0.f};

  for (int j0 = 0; j0 <= q0; j0 += 64) {
    __syncthreads();
    // stage K tile: [64 keys][128 d] in fragment order
#pragma unroll
    for (int it = 0; it < 4; it++) {
      int idx = it * 256 + tid;
      int key = idx >> 4, dc = idx & 15;
      *(uint4*)&Ks[(dc * 64 + key) * 8] =
          *(const uint4*)(Vm != Km ?  // (dummy select avoided; plain Km)
              Km + (size_t)(b * S_ + j0 + key) * (NKV_ * HD_) + kvh * HD_ + dc * 8 :
              Km + (size_t)(b * S_ + j0 + key) * (NKV_ * HD_) + kvh * HD_ + dc * 8);
    }
    // stage V transposed: element (key,d) -> chunk (key>>3)*128+d, slot key&7
#pragma unroll
    for (int it = 0; it < 4; it++) {
      int idx = it * 256 + tid;
      int key = idx >> 4, dc = idx & 15;
      bf16x8 v = *(const bf16x8*)(Vm + (size_t)(b * S_ + j0 + key) * (NKV_ * HD_) + kvh * HD_ + dc * 8);
#pragma unroll
      for (int e = 0; e < 8; e++)
        Vt[((key >> 3) * 128 + dc * 8 + e) * 8 + (key & 7)] = v[e];
    }
    __syncthreads();

    // scores: 16x64 per wave
    f32x4 sc4[4];
#pragma unroll
    for (int nt = 0; nt < 4; nt++) sc4[nt] = (f32x4){0.f, 0.f, 0.f, 0.f};
#pragma unroll
    for (int kt = 0; kt < 4; kt++) {
#pragma unroll
      for (int nt = 0; nt < 4; nt++) {
        bf16x8 bk = *(const bf16x8*)&Ks[((kt * 4 + quad) * 64 + nt * 16 + l16) * 8];
        sc4[nt] = __builtin_amdgcn_mfma_f32_16x16x32_bf16(aQ[kt], bk, sc4[nt], 0, 0, 0);
      }
    }

    // scale + causal mask + online softmax
    int rowbase = q0 + wave * 16 + quad * 4;
    float rmax[4] = {-1e30f, -1e30f, -1e30f, -1e30f};
#pragma unroll
    for (int nt = 0; nt < 4; nt++) {
      int col = j0 + nt * 16 + l16;
#pragma unroll
      for (int r = 0; r < 4; r++) {
        float v = sc4[nt][r] * scaling;
        if (col > rowbase + r) v += -1e9f;
        sc4[nt][r] = v;
        rmax[r] = fmaxf(rmax[r], v);
      }
    }
#pragma unroll
    for (int m = 1; m < 16; m <<= 1)
#pragma unroll
      for (int r = 0; r < 4; r++)
        rmax[r] = fmaxf(rmax[r], __shfl_xor(rmax[r], m));
    float alpha[4];
#pragma unroll
    for (int r = 0; r < 4; r++) {
      float mnew = fmaxf(mcur[r], rmax[r]);
      alpha[r] = __expf(mcur[r] - mnew);
      mcur[r] = mnew;
    }
    float rsum[4] = {0.f, 0.f, 0.f, 0.f};
#pragma unroll
    for (int nt = 0; nt < 4; nt++)
#pragma unroll
      for (int r = 0; r < 4; r++) {
        float p = __expf(sc4[nt][r] - mcur[r]);
        sc4[nt][r] = p;
        rsum[r] += p;
      }
#pragma unroll
    for (int m = 1; m < 16; m <<= 1)
#pragma unroll
      for (int r = 0; r < 4; r++)
        rsum[r] += __shfl_xor(rsum[r], m);
#pragma unroll
    for (int r = 0; r < 4; r++) lcur[r] = lcur[r] * alpha[r] + rsum[r];
#pragma unroll
    for (int n = 0; n < 8; n++)
#pragma unroll
      for (int r = 0; r < 4; r++) O[n][r] *= alpha[r];

    // write P (C-layout) to per-wave LDS region in A-frag layout
#pragma unroll
    for (int nt = 0; nt < 4; nt++) {
      int col = nt * 16 + l16;
#pragma unroll
      for (int r = 0; r < 4; r++)
        Ps[wave * 1024 + ((col >> 3) * 16 + quad * 4 + r) * 8 + (col & 7)] = (bf16)sc4[nt][r];
    }

    // ctx += P * V   (key-dim 64 = 2 K-steps of 32; HD 128 = 8 n-tiles)
#pragma unroll
    for (int kt = 0; kt < 2; kt++) {
      bf16x8 ap = *(const bf16x8*)&Ps[wave * 1024 + ((kt * 4 + quad) * 16 + l16) * 8];
#pragma unroll
      for (int n = 0; n < 8; n++) {
        bf16x8 bv = *(const bf16x8*)&Vt[((kt * 4 + quad) * 128 + n * 16 + l16) * 8];
        O[n] = __builtin_amdgcn_mfma_f32_16x16x32_bf16(ap, bv, O[n], 0, 0, 0);
      }
    }
  }

  // epilogue: ctx[b][s][h*128+d] bf16
  size_t obase = (size_t)(b * S_ + q0 + wave * 16 + quad * 4) * (NH_ * HD_) + h * HD_;
#pragma unroll
  for (int n = 0; n < 8; n++)
#pragma unroll
    for (int r = 0; r < 4; r++)
      Cm[obase + (size_t)r * (NH_ * HD_) + n * 16 + l16] = (bf16)(O[n][r] / lcur[r]);
}

extern "C" void kernel_launch(void* const* d_in, const int* in_sizes, int n_in,
                              void* d_out, int out_size, void* d_ws, size_t ws_size,
                              hipStream_t stream) {
  const float* hidden = (const float*)d_in[0];
  const float* cosT   = (const float*)d_in[1];
  const float* sinT   = (const float*)d_in[2];
  // d_in[3] attention_mask: exactly causal 0/-1e9 -> implemented directly
  const int*   q_qw = (const int*)d_in[4];
  const float* q_sc = (const float*)d_in[5];
  const int*   k_qw = (const int*)d_in[6];
  const float* k_sc = (const float*)d_in[7];
  const int*   v_qw = (const int*)d_in[8];
  const float* v_sc = (const float*)d_in[9];
  const int*   o_qw = (const int*)d_in[10];
  const float* o_sc = (const float*)d_in[11];

  const size_t MB = 1024 * 1024;
  char* ws = (char*)d_ws;
  bf16* Xb = (bf16*)(ws);             // 32MB  hidden bf16; later reused as ctx
  bf16* Wb = (bf16*)(ws + 32 * MB);   // 32MB  current dequantized weight
  bf16* Qm = (bf16*)(ws + 64 * MB);   // 32MB  [T][4096]
  bf16* Km = (bf16*)(ws + 96 * MB);   // 8MB   [T][1024]
  bf16* Vm = (bf16*)(ws + 104 * MB);  // 8MB   [T][1024]   (total 112MB)
  bf16* Cm = Xb;                      // ctx aliases Xb (dead after V gemm)

  cvt_bf16_kernel<<<(T_ * HID_ / 4 + 255) / 256, 256, 0, stream>>>(hidden, Xb, T_ * HID_ / 4);

  // Q projection + rope
  dequant_kernel<<<(4096 * 512 + 255) / 256, 256, 0, stream>>>(q_qw, q_sc, Wb, 4096, 4096);
  gemm_bt_kernel<<<dim3(64, 64), 256, 0, stream>>>(Xb, Wb, Qm, 4096, 4096, 0);
  rope_kernel<<<(T_ * NH_ * 64 + 255) / 256, 256, 0, stream>>>(Qm, cosT, sinT, NH_);

  // K projection + rope
  dequant_kernel<<<(1024 * 512 + 255) / 256, 256, 0, stream>>>(k_qw, k_sc, Wb, 1024, 4096);
  gemm_bt_kernel<<<dim3(16, 64), 256, 0, stream>>>(Xb, Wb, Km, 1024, 4096, 0);
  rope_kernel<<<(T_ * NKV_ * 64 + 255) / 256, 256, 0, stream>>>(Km, cosT, sinT, NKV_);

  // V projection
  dequant_kernel<<<(1024 * 512 + 255) / 256, 256, 0, stream>>>(v_qw, v_sc, Wb, 1024, 4096);
  gemm_bt_kernel<<<dim3(16, 64), 256, 0, stream>>>(Xb, Wb, Vm, 1024, 4096, 0);

  // attention (writes Cm = Xb region; Xb consumed)
  attn_kernel<<<dim3(S_ / 64, NH_, B_), 256, 0, stream>>>(Qm, Km, Vm, Cm);

  // output projection -> fp32 d_out
  dequant_kernel<<<(4096 * 512 + 255) / 256, 256, 0, stream>>>(o_qw, o_sc, Wb, 4096, 4096);
  gemm_bt_kernel<<<dim3(64, 64), 256, 0, stream>>>(Cm, Wb, d_out, 4096, 4096, 1);
}

// Round 2
// 1147.654 us; speedup vs baseline: 1.7298x; 1.7298x over previous
//
#include <hip/hip_runtime.h>
#include <hip/hip_bf16.h>

#define B_ 2
#define S_ 2048
#define HID_ 4096
#define NH_ 32
#define NKV_ 8
#define HD_ 128
#define T_ (B_*S_)

typedef __bf16 bf16;
typedef __bf16 bf16x8 __attribute__((ext_vector_type(8)));
typedef __bf16 bf16x4 __attribute__((ext_vector_type(4)));
typedef float f32x4 __attribute__((ext_vector_type(4)));

// async global->LDS, 16B per lane; LDS dest = base + lane*16 (wave-uniform base)
__device__ __forceinline__ void load_lds16(const void* g, void* l) {
  __builtin_amdgcn_global_load_lds((const __attribute__((address_space(1))) void*)g,
                                   (__attribute__((address_space(3))) void*)l, 16, 0, 0);
}

// ---------------- convert fp32 -> bf16 ----------------
__global__ __launch_bounds__(256) void cvt_bf16_kernel(const float* __restrict__ in,
                                                       bf16* __restrict__ out, int n4) {
  int idx = blockIdx.x * 256 + threadIdx.x;
  if (idx >= n4) return;
  float4 v = ((const float4*)in)[idx];
  bf16x4 o;
  o.x = (bf16)v.x; o.y = (bf16)v.y; o.z = (bf16)v.z; o.w = (bf16)v.w;
  ((bf16x4*)out)[idx] = o;
}

// ---------------- dequant int4(stored int32) -> bf16 ----------------
__global__ __launch_bounds__(256) void dequant_kernel(const int* __restrict__ qw,
                                                      const float* __restrict__ scale,
                                                      bf16* __restrict__ out,
                                                      int OD, int ID) {
  int idx = blockIdx.x * 256 + threadIdx.x;
  int perRow = ID >> 3;
  int total = OD * perRow;
  if (idx >= total) return;
  int o = idx / perRow;
  int ic = idx - o * perRow;
  float s = scale[o * (ID >> 7) + ((ic * 8) >> 7)];
  const int* q = qw + (size_t)o * ID + ic * 8;
  int4 q0 = *(const int4*)q;
  int4 q1 = *(const int4*)(q + 4);
  bf16x8 r;
  r[0] = (bf16)((q0.x - 8) * s);
  r[1] = (bf16)((q0.y - 8) * s);
  r[2] = (bf16)((q0.z - 8) * s);
  r[3] = (bf16)((q0.w - 8) * s);
  r[4] = (bf16)((q1.x - 8) * s);
  r[5] = (bf16)((q1.y - 8) * s);
  r[6] = (bf16)((q1.z - 8) * s);
  r[7] = (bf16)((q1.w - 8) * s);
  *(bf16x8*)(out + (size_t)o * ID + ic * 8) = r;
}

// ---------------- GEMM: C[M][N] = A[M][K] * B[N][K]^T ----------------
// 128x128 tile, BK=64, 256 threads = 4 waves in 2x2; m97 structure with
// global_load_lds(16B) staging. LDS layout: addr(row, kchunk) =
// row*128B + ((kchunk ^ (row&7))*16)B  (XOR swizzle on the GLOBAL chunk so
// frag reads spread over 8 bank-groups; global coalescing preserved).
__global__ __launch_bounds__(256) void gemm_bt_kernel(const bf16* __restrict__ A,
                                                      const bf16* __restrict__ Bm,
                                                      void* __restrict__ Cout,
                                                      int N, int K, int c_fp32) {
  __shared__ bf16 As[8192];   // 16KB
  __shared__ bf16 Bs[8192];   // 16KB
  int tid = threadIdx.x;
  int wave = tid >> 6, lane = tid & 63, quad = lane >> 4, l16 = lane & 15;
  int m0 = blockIdx.y * 128, n0 = blockIdx.x * 128;
  int wm = (wave >> 1) * 64, wn = (wave & 1) * 64;

  // staging geometry: block t = 8 rows; lane -> row 8t+(lane>>3), slot lane&7
  int srow = lane >> 3;
  int schunk = (lane & 7) ^ (srow & 7);
  const bf16* Ab[4];
  const bf16* Bb[4];
#pragma unroll
  for (int u = 0; u < 4; u++) {
    int t = wave + 4 * u;
    Ab[u] = A  + (size_t)(m0 + 8 * t + srow) * K + schunk * 8;
    Bb[u] = Bm + (size_t)(n0 + 8 * t + srow) * K + schunk * 8;
  }

  f32x4 acc[4][4];
#pragma unroll
  for (int mt = 0; mt < 4; mt++)
#pragma unroll
    for (int nt = 0; nt < 4; nt++) acc[mt][nt] = (f32x4){0.f, 0.f, 0.f, 0.f};

  for (int k0 = 0; k0 < K; k0 += 64) {
    __syncthreads();
#pragma unroll
    for (int u = 0; u < 4; u++) {
      int t = wave + 4 * u;
      load_lds16(Ab[u] + k0, (char*)As + t * 1024);
      load_lds16(Bb[u] + k0, (char*)Bs + t * 1024);
    }
    __syncthreads();
#pragma unroll
    for (int kk = 0; kk < 2; kk++) {
      bf16x8 af[4], bfr[4];
#pragma unroll
      for (int mt = 0; mt < 4; mt++) {
        int r = wm + mt * 16 + l16;
        af[mt] = *(const bf16x8*)((const char*)As + r * 128 + (((kk * 4 + quad) ^ (r & 7)) << 4));
      }
#pragma unroll
      for (int nt = 0; nt < 4; nt++) {
        int r = wn + nt * 16 + l16;
        bfr[nt] = *(const bf16x8*)((const char*)Bs + r * 128 + (((kk * 4 + quad) ^ (r & 7)) << 4));
      }
#pragma unroll
      for (int mt = 0; mt < 4; mt++)
#pragma unroll
        for (int nt = 0; nt < 4; nt++)
          acc[mt][nt] = __builtin_amdgcn_mfma_f32_16x16x32_bf16(af[mt], bfr[nt], acc[mt][nt], 0, 0, 0);
    }
  }

#pragma unroll
  for (int mt = 0; mt < 4; mt++)
#pragma unroll
    for (int nt = 0; nt < 4; nt++)
#pragma unroll
      for (int r = 0; r < 4; r++) {
        int rr = m0 + wm + mt * 16 + quad * 4 + r;
        int cc = n0 + wn + nt * 16 + l16;
        if (c_fp32) ((float*)Cout)[(size_t)rr * N + cc] = acc[mt][nt][r];
        else        ((bf16*)Cout)[(size_t)rr * N + cc] = (bf16)acc[mt][nt][r];
      }
}

// ---------------- RoPE (in place, on [T][nheads*128] bf16), folds scale ----------------
__global__ __launch_bounds__(256) void rope_kernel(bf16* __restrict__ X,
                                                   const float* __restrict__ cosT,
                                                   const float* __restrict__ sinT,
                                                   int nheads, float outscale) {
  int idx = blockIdx.x * 256 + threadIdx.x;
  int total = T_ * nheads * 64;
  if (idx >= total) return;
  int d0 = idx & 63;
  int h = (idx >> 6) & (nheads - 1);
  int t = idx / (nheads * 64);
  size_t base = (size_t)t * (nheads * 128) + h * 128;
  float x1 = (float)X[base + d0];
  float x2 = (float)X[base + d0 + 64];
  float c1 = cosT[t * 128 + d0],      s1 = sinT[t * 128 + d0];
  float c2 = cosT[t * 128 + d0 + 64], s2 = sinT[t * 128 + d0 + 64];
  X[base + d0]      = (bf16)((x1 * c1 - x2 * s1) * outscale);
  X[base + d0 + 64] = (bf16)((x2 * c2 + x1 * s2) * outscale);
}

// ---------------- fused causal GQA attention (flash-style) ----------------
// grid (S/128, NH, B); 256 threads = 4 waves; wave owns 32 Q rows (2 m-tiles).
// K staged natural [key][128d] (swizzled), V staged from global V^T [d][key]
// (swizzled) -- both via global_load_lds 16B. P via padded per-wave LDS.
__global__ __launch_bounds__(256) void attn_kernel(const bf16* __restrict__ Qm,
                                                   const bf16* __restrict__ Km,
                                                   const bf16* __restrict__ VtG,
                                                   bf16* __restrict__ Cm) {
  __shared__ bf16 Ks[8192];        // 16KB: addr(key, dc16) = key*256B + ((dc^(key&7))<<4)
  __shared__ bf16 Vt[8192];        // 16KB: addr(d, kc8)   = d*128B   + ((kc^(d&7))<<4)
  __shared__ bf16 Ps[4 * 2112];    // per-wave P: chunk stride 264 elems (8 pad)
  int tid = threadIdx.x;
  int wave = tid >> 6, lane = tid & 63, quad = lane >> 4, l16 = lane & 15;
  int qt = blockIdx.x, h = blockIdx.y, b = blockIdx.z;
  int kvh = h >> 2;
  int q0 = qt * 128;

  // Q fragments (scale already folded in at rope): A[m=l16][k=quad*8+j]
  bf16x8 aQ[2][4];
#pragma unroll
  for (int mt = 0; mt < 2; mt++) {
    int row = q0 + wave * 32 + mt * 16 + l16;
    const bf16* qb = Qm + (size_t)(b * S_ + row) * (NH_ * HD_) + h * HD_;
#pragma unroll
    for (int kt = 0; kt < 4; kt++)
      aQ[mt][kt] = *(const bf16x8*)(qb + kt * 32 + quad * 8);
  }

  // staging base pointers
  const bf16* Kb[4];
  const bf16* Vb[4];
  {
    int r4 = lane >> 4, c16 = lane & 15;
    int r8 = lane >> 3, c8 = lane & 7;
#pragma unroll
    for (int u = 0; u < 4; u++) {
      int t = wave + 4 * u;
      int krow = 4 * t + r4;
      int kc = c16 ^ (krow & 7);
      Kb[u] = Km + (size_t)(b * S_ + krow) * (NKV_ * HD_) + kvh * HD_ + kc * 8;
      int vrow = 8 * t + r8;
      int vc = c8 ^ (vrow & 7);
      Vb[u] = VtG + (size_t)(kvh * HD_ + vrow) * T_ + b * S_ + vc * 8;
    }
  }

  float mcur[2][4], lcur[2][4];
  f32x4 O[2][8];
#pragma unroll
  for (int mt = 0; mt < 2; mt++)
#pragma unroll
    for (int r = 0; r < 4; r++) { mcur[mt][r] = -1e30f; lcur[mt][r] = 0.f; }
#pragma unroll
  for (int mt = 0; mt < 2; mt++)
#pragma unroll
    for (int n = 0; n < 8; n++) O[mt][n] = (f32x4){0.f, 0.f, 0.f, 0.f};

  for (int j0 = 0; j0 < q0 + 128; j0 += 64) {
    __syncthreads();
#pragma unroll
    for (int u = 0; u < 4; u++) {
      int t = wave + 4 * u;
      load_lds16(Kb[u] + (size_t)j0 * (NKV_ * HD_), (char*)Ks + t * 1024);
      load_lds16(Vb[u] + j0,                        (char*)Vt + t * 1024);
    }
    __syncthreads();

    // scores: 32x64 per wave
    f32x4 sc[2][4];
#pragma unroll
    for (int mt = 0; mt < 2; mt++)
#pragma unroll
      for (int nt = 0; nt < 4; nt++) sc[mt][nt] = (f32x4){0.f, 0.f, 0.f, 0.f};
#pragma unroll
    for (int kt = 0; kt < 4; kt++) {
      bf16x8 bk[4];
#pragma unroll
      for (int nt = 0; nt < 4; nt++) {
        int key = nt * 16 + l16;
        bk[nt] = *(const bf16x8*)((const char*)Ks + key * 256 + (((kt * 4 + quad) ^ (key & 7)) << 4));
      }
#pragma unroll
      for (int mt = 0; mt < 2; mt++)
#pragma unroll
        for (int nt = 0; nt < 4; nt++)
          sc[mt][nt] = __builtin_amdgcn_mfma_f32_16x16x32_bf16(aQ[mt][kt], bk[nt], sc[mt][nt], 0, 0, 0);
    }

    // mask + online softmax + P store, per m-tile
#pragma unroll
    for (int mt = 0; mt < 2; mt++) {
      int rowb = q0 + wave * 32 + mt * 16 + quad * 4;
      float rmax[4] = {-1e30f, -1e30f, -1e30f, -1e30f};
#pragma unroll
      for (int nt = 0; nt < 4; nt++) {
        int col = j0 + nt * 16 + l16;
#pragma unroll
        for (int r = 0; r < 4; r++) {
          float v = sc[mt][nt][r] + ((col > rowb + r) ? -1e9f : 0.f);
          sc[mt][nt][r] = v;
          rmax[r] = fmaxf(rmax[r], v);
        }
      }
#pragma unroll
      for (int m = 1; m < 16; m <<= 1)
#pragma unroll
        for (int r = 0; r < 4; r++)
          rmax[r] = fmaxf(rmax[r], __shfl_xor(rmax[r], m));
      float alpha[4];
#pragma unroll
      for (int r = 0; r < 4; r++) {
        float mnew = fmaxf(mcur[mt][r], rmax[r]);
        alpha[r] = __expf(mcur[mt][r] - mnew);
        mcur[mt][r] = mnew;
      }
      float rsum[4] = {0.f, 0.f, 0.f, 0.f};
#pragma unroll
      for (int nt = 0; nt < 4; nt++)
#pragma unroll
        for (int r = 0; r < 4; r++) {
          float p = __expf(sc[mt][nt][r] - mcur[mt][r]);
          sc[mt][nt][r] = p;
          rsum[r] += p;
        }
#pragma unroll
      for (int m = 1; m < 16; m <<= 1)
#pragma unroll
        for (int r = 0; r < 4; r++)
          rsum[r] += __shfl_xor(rsum[r], m);
#pragma unroll
      for (int r = 0; r < 4; r++) lcur[mt][r] = lcur[mt][r] * alpha[r] + rsum[r];
#pragma unroll
      for (int n = 0; n < 8; n++)
#pragma unroll
        for (int r = 0; r < 4; r++) O[mt][n][r] *= alpha[r];
      // store P in A-frag layout (wave-private region, no barrier needed)
#pragma unroll
      for (int nt = 0; nt < 4; nt++) {
        int key = nt * 16 + l16;
#pragma unroll
        for (int r = 0; r < 4; r++)
          Ps[wave * 2112 + (key >> 3) * 264 + (mt * 16 + quad * 4 + r) * 8 + (key & 7)] = (bf16)sc[mt][nt][r];
      }
    }

    // ctx += P * V
#pragma unroll
    for (int kt = 0; kt < 2; kt++) {
      bf16x8 ap[2];
#pragma unroll
      for (int mt = 0; mt < 2; mt++)
        ap[mt] = *(const bf16x8*)&Ps[wave * 2112 + (kt * 4 + quad) * 264 + (mt * 16 + l16) * 8];
#pragma unroll
      for (int nt = 0; nt < 8; nt++) {
        int d = nt * 16 + l16;
        bf16x8 bv = *(const bf16x8*)((const char*)Vt + d * 128 + (((kt * 4 + quad) ^ (d & 7)) << 4));
#pragma unroll
        for (int mt = 0; mt < 2; mt++)
          O[mt][nt] = __builtin_amdgcn_mfma_f32_16x16x32_bf16(ap[mt], bv, O[mt][nt], 0, 0, 0);
      }
    }
  }

  // epilogue
#pragma unroll
  for (int mt = 0; mt < 2; mt++)
#pragma unroll
    for (int nt = 0; nt < 8; nt++)
#pragma unroll
      for (int r = 0; r < 4; r++) {
        int row = q0 + wave * 32 + mt * 16 + quad * 4 + r;
        Cm[(size_t)(b * S_ + row) * (NH_ * HD_) + h * HD_ + nt * 16 + l16] =
            (bf16)(O[mt][nt][r] / lcur[mt][r]);
      }
}

extern "C" void kernel_launch(void* const* d_in, const int* in_sizes, int n_in,
                              void* d_out, int out_size, void* d_ws, size_t ws_size,
                              hipStream_t stream) {
  const float* hidden = (const float*)d_in[0];
  const float* cosT   = (const float*)d_in[1];
  const float* sinT   = (const float*)d_in[2];
  const int*   q_qw = (const int*)d_in[4];
  const float* q_sc = (const float*)d_in[5];
  const int*   k_qw = (const int*)d_in[6];
  const float* k_sc = (const float*)d_in[7];
  const int*   v_qw = (const int*)d_in[8];
  const float* v_sc = (const float*)d_in[9];
  const int*   o_qw = (const int*)d_in[10];
  const float* o_sc = (const float*)d_in[11];

  const size_t MB = 1024 * 1024;
  char* ws = (char*)d_ws;
  bf16* Xb  = (bf16*)(ws);             // 32MB  hidden bf16; later reused as ctx
  bf16* Wb  = (bf16*)(ws + 32 * MB);   // 32MB  current dequantized weight
  bf16* Qm  = (bf16*)(ws + 64 * MB);   // 32MB  [T][4096]
  bf16* Km  = (bf16*)(ws + 96 * MB);   // 8MB   [T][1024]
  bf16* VtG = (bf16*)(ws + 104 * MB);  // 8MB   [1024][T]  (V transposed)
  bf16* Cm  = Xb;

  cvt_bf16_kernel<<<(T_ * HID_ / 4 + 255) / 256, 256, 0, stream>>>(hidden, Xb, T_ * HID_ / 4);

  const float scaling = 0.08838834764831845f;  // 1/sqrt(128)

  // Q projection + rope (scale folded into Q)
  dequant_kernel<<<(4096 * 512 + 255) / 256, 256, 0, stream>>>(q_qw, q_sc, Wb, 4096, 4096);
  gemm_bt_kernel<<<dim3(32, 32), 256, 0, stream>>>(Xb, Wb, Qm, 4096, 4096, 0);
  rope_kernel<<<(T_ * NH_ * 64 + 255) / 256, 256, 0, stream>>>(Qm, cosT, sinT, NH_, scaling);

  // K projection + rope
  dequant_kernel<<<(1024 * 512 + 255) / 256, 256, 0, stream>>>(k_qw, k_sc, Wb, 1024, 4096);
  gemm_bt_kernel<<<dim3(8, 32), 256, 0, stream>>>(Xb, Wb, Km, 1024, 4096, 0);
  rope_kernel<<<(T_ * NKV_ * 64 + 255) / 256, 256, 0, stream>>>(Km, cosT, sinT, NKV_, 1.0f);

  // V projection, written TRANSPOSED: V^T[1024][T] = Wv * X^T
  dequant_kernel<<<(1024 * 512 + 255) / 256, 256, 0, stream>>>(v_qw, v_sc, Wb, 1024, 4096);
  gemm_bt_kernel<<<dim3(32, 8), 256, 0, stream>>>(Wb, Xb, VtG, 4096, 4096, 0);

  // attention (writes Cm = Xb region; Xb consumed)
  attn_kernel<<<dim3(S_ / 128, NH_, B_), 256, 0, stream>>>(Qm, Km, VtG, Cm);

  // output projection -> fp32 d_out
  dequant_kernel<<<(4096 * 512 + 255) / 256, 256, 0, stream>>>(o_qw, o_sc, Wb, 4096, 4096);
  gemm_bt_kernel<<<dim3(32, 32), 256, 0, stream>>>(Cm, Wb, d_out, 4096, 4096, 1);
}

// Round 3
// 1035.134 us; speedup vs baseline: 1.9178x; 1.1087x over previous
//
#include <hip/hip_runtime.h>
#include <hip/hip_bf16.h>

#define B_ 2
#define S_ 2048
#define HID_ 4096
#define NH_ 32
#define NKV_ 8
#define HD_ 128
#define T_ (B_*S_)

typedef __bf16 bf16;
typedef __bf16 bf16x8 __attribute__((ext_vector_type(8)));
typedef __bf16 bf16x4 __attribute__((ext_vector_type(4)));
typedef float f32x4 __attribute__((ext_vector_type(4)));

// async global->LDS, 16B per lane; LDS dest = base + lane*16 (wave-uniform base)
__device__ __forceinline__ void load_lds16(const void* g, void* l) {
  __builtin_amdgcn_global_load_lds((const __attribute__((address_space(1))) void*)g,
                                   (__attribute__((address_space(3))) void*)l, 16, 0, 0);
}

// ---------------- convert fp32 -> bf16 ----------------
__global__ __launch_bounds__(256) void cvt_bf16_kernel(const float* __restrict__ in,
                                                       bf16* __restrict__ out, int n4) {
  int idx = blockIdx.x * 256 + threadIdx.x;
  if (idx >= n4) return;
  float4 v = ((const float4*)in)[idx];
  bf16x4 o;
  o.x = (bf16)v.x; o.y = (bf16)v.y; o.z = (bf16)v.z; o.w = (bf16)v.w;
  ((bf16x4*)out)[idx] = o;
}

// ---------------- dequant int4(stored int32) -> bf16 ----------------
__global__ __launch_bounds__(256) void dequant_kernel(const int* __restrict__ qw,
                                                      const float* __restrict__ scale,
                                                      bf16* __restrict__ out,
                                                      int OD, int ID) {
  int idx = blockIdx.x * 256 + threadIdx.x;
  int perRow = ID >> 3;
  int total = OD * perRow;
  if (idx >= total) return;
  int o = idx / perRow;
  int ic = idx - o * perRow;
  float s = scale[o * (ID >> 7) + ((ic * 8) >> 7)];
  const int* q = qw + (size_t)o * ID + ic * 8;
  int4 q0 = *(const int4*)q;
  int4 q1 = *(const int4*)(q + 4);
  bf16x8 r;
  r[0] = (bf16)((q0.x - 8) * s);
  r[1] = (bf16)((q0.y - 8) * s);
  r[2] = (bf16)((q0.z - 8) * s);
  r[3] = (bf16)((q0.w - 8) * s);
  r[4] = (bf16)((q1.x - 8) * s);
  r[5] = (bf16)((q1.y - 8) * s);
  r[6] = (bf16)((q1.z - 8) * s);
  r[7] = (bf16)((q1.w - 8) * s);
  *(bf16x8*)(out + (size_t)o * ID + ic * 8) = r;
}

// ---------------- GEMM: C[M][N] = A[M][K] * B[N][K]^T (plain) ----------------
// 128x128 tile, BK=64, 256 threads = 4 waves in 2x2; global_load_lds(16B);
// LDS addr(row, kchunk) = row*128B + ((kchunk ^ (row&7))*16)B.
__global__ __launch_bounds__(256) void gemm_bt_kernel(const bf16* __restrict__ A,
                                                      const bf16* __restrict__ Bm,
                                                      void* __restrict__ Cout,
                                                      int N, int K, int c_fp32) {
  __shared__ bf16 As[8192];
  __shared__ bf16 Bs[8192];
  int tid = threadIdx.x;
  int wave = tid >> 6, lane = tid & 63, quad = lane >> 4, l16 = lane & 15;
  int m0 = blockIdx.y * 128, n0 = blockIdx.x * 128;
  int wm = (wave >> 1) * 64, wn = (wave & 1) * 64;

  int srow = lane >> 3;
  int schunk = (lane & 7) ^ (srow & 7);
  const bf16* Ab[4];
  const bf16* Bb[4];
#pragma unroll
  for (int u = 0; u < 4; u++) {
    int t = wave + 4 * u;
    Ab[u] = A  + (size_t)(m0 + 8 * t + srow) * K + schunk * 8;
    Bb[u] = Bm + (size_t)(n0 + 8 * t + srow) * K + schunk * 8;
  }

  f32x4 acc[4][4];
#pragma unroll
  for (int mt = 0; mt < 4; mt++)
#pragma unroll
    for (int nt = 0; nt < 4; nt++) acc[mt][nt] = (f32x4){0.f, 0.f, 0.f, 0.f};

  for (int k0 = 0; k0 < K; k0 += 64) {
    __syncthreads();
#pragma unroll
    for (int u = 0; u < 4; u++) {
      int t = wave + 4 * u;
      load_lds16(Ab[u] + k0, (char*)As + t * 1024);
      load_lds16(Bb[u] + k0, (char*)Bs + t * 1024);
    }
    __syncthreads();
#pragma unroll
    for (int kk = 0; kk < 2; kk++) {
      bf16x8 af[4], bfr[4];
#pragma unroll
      for (int mt = 0; mt < 4; mt++) {
        int r = wm + mt * 16 + l16;
        af[mt] = *(const bf16x8*)((const char*)As + r * 128 + (((kk * 4 + quad) ^ (r & 7)) << 4));
      }
#pragma unroll
      for (int nt = 0; nt < 4; nt++) {
        int r = wn + nt * 16 + l16;
        bfr[nt] = *(const bf16x8*)((const char*)Bs + r * 128 + (((kk * 4 + quad) ^ (r & 7)) << 4));
      }
#pragma unroll
      for (int mt = 0; mt < 4; mt++)
#pragma unroll
        for (int nt = 0; nt < 4; nt++)
          acc[mt][nt] = __builtin_amdgcn_mfma_f32_16x16x32_bf16(af[mt], bfr[nt], acc[mt][nt], 0, 0, 0);
    }
  }

#pragma unroll
  for (int mt = 0; mt < 4; mt++)
#pragma unroll
    for (int nt = 0; nt < 4; nt++)
#pragma unroll
      for (int r = 0; r < 4; r++) {
        int rr = m0 + wm + mt * 16 + quad * 4 + r;
        int cc = n0 + wn + nt * 16 + l16;
        if (c_fp32) ((float*)Cout)[(size_t)rr * N + cc] = acc[mt][nt][r];
        else        ((bf16*)Cout)[(size_t)rr * N + cc] = (bf16)acc[mt][nt][r];
      }
}

// ---------------- GEMM + fused RoPE epilogue (for Q and K projections) --------
// Same main loop; epilogue pairs d <-> d+64 via partner wave (wave^1) using a
// 17-float-stride LDS exchange (conflict-free), applies rope + scale.
__global__ __launch_bounds__(256) void gemm_rope_kernel(const bf16* __restrict__ A,
                                                        const bf16* __restrict__ Bm,
                                                        bf16* __restrict__ Out,
                                                        int N, int K,
                                                        const float* __restrict__ cosT,
                                                        const float* __restrict__ sinT,
                                                        float outscale) {
  __shared__ char smem[32768];
  bf16* As = (bf16*)smem;
  bf16* Bs = (bf16*)(smem + 16384);
  float* Ex = (float*)smem;   // 256*17 floats = 17408B, aliases As/Bs after loop
  int tid = threadIdx.x;
  int wave = tid >> 6, lane = tid & 63, quad = lane >> 4, l16 = lane & 15;
  int m0 = blockIdx.y * 128, n0 = blockIdx.x * 128;
  int wm = (wave >> 1) * 64, wn = (wave & 1) * 64;

  int srow = lane >> 3;
  int schunk = (lane & 7) ^ (srow & 7);
  const bf16* Ab[4];
  const bf16* Bb[4];
#pragma unroll
  for (int u = 0; u < 4; u++) {
    int t = wave + 4 * u;
    Ab[u] = A  + (size_t)(m0 + 8 * t + srow) * K + schunk * 8;
    Bb[u] = Bm + (size_t)(n0 + 8 * t + srow) * K + schunk * 8;
  }

  f32x4 acc[4][4];
#pragma unroll
  for (int mt = 0; mt < 4; mt++)
#pragma unroll
    for (int nt = 0; nt < 4; nt++) acc[mt][nt] = (f32x4){0.f, 0.f, 0.f, 0.f};

  for (int k0 = 0; k0 < K; k0 += 64) {
    __syncthreads();
#pragma unroll
    for (int u = 0; u < 4; u++) {
      int t = wave + 4 * u;
      load_lds16(Ab[u] + k0, (char*)As + t * 1024);
      load_lds16(Bb[u] + k0, (char*)Bs + t * 1024);
    }
    __syncthreads();
#pragma unroll
    for (int kk = 0; kk < 2; kk++) {
      bf16x8 af[4], bfr[4];
#pragma unroll
      for (int mt = 0; mt < 4; mt++) {
        int r = wm + mt * 16 + l16;
        af[mt] = *(const bf16x8*)((const char*)As + r * 128 + (((kk * 4 + quad) ^ (r & 7)) << 4));
      }
#pragma unroll
      for (int nt = 0; nt < 4; nt++) {
        int r = wn + nt * 16 + l16;
        bfr[nt] = *(const bf16x8*)((const char*)Bs + r * 128 + (((kk * 4 + quad) ^ (r & 7)) << 4));
      }
#pragma unroll
      for (int mt = 0; mt < 4; mt++)
#pragma unroll
        for (int nt = 0; nt < 4; nt++)
          acc[mt][nt] = __builtin_amdgcn_mfma_f32_16x16x32_bf16(af[mt], bfr[nt], acc[mt][nt], 0, 0, 0);
    }
  }

  int myb = tid * 17;
  int pb = (tid ^ 64) * 17;    // partner: other wn half, same lane/registers
#pragma unroll
  for (int mt = 0; mt < 4; mt++) {
    __syncthreads();
#pragma unroll
    for (int nt = 0; nt < 4; nt++)
#pragma unroll
      for (int r = 0; r < 4; r++)
        Ex[myb + nt * 4 + r] = acc[mt][nt][r];
    __syncthreads();
    int rowb = m0 + wm + mt * 16 + quad * 4;
#pragma unroll
    for (int nt = 0; nt < 4; nt++) {
      int cc = n0 + wn + nt * 16 + l16;
      int d = cc & 127;
#pragma unroll
      for (int r = 0; r < 4; r++) {
        int row = rowb + r;
        int t = row & (S_ - 1);
        float self = acc[mt][nt][r];
        float other = Ex[pb + nt * 4 + r];
        float c = cosT[t * 128 + d], s = sinT[t * 128 + d];
        float o = (d < 64) ? (self * c - other * s) : (self * c + other * s);
        Out[(size_t)row * N + cc] = (bf16)(o * outscale);
      }
    }
  }
}

// ---------------- fused causal GQA attention (flash-style, paired tiles) ------
// grid (8, NH, B); block processes q-tiles qt=blockIdx.x and 15-blockIdx.x
// sequentially -> uniform 34 j-iterations per block; 512 blocks = 2/CU steady.
__global__ __launch_bounds__(256) void attn_kernel(const bf16* __restrict__ Qm,
                                                   const bf16* __restrict__ Km,
                                                   const bf16* __restrict__ VtG,
                                                   bf16* __restrict__ Cm) {
  __shared__ bf16 Ks[8192];        // addr(key, dc16) = key*256B + ((dc^(key&7))<<4)
  __shared__ bf16 Vt[8192];        // addr(d, kc8)   = d*128B   + ((kc^(d&7))<<4)
  __shared__ bf16 Ps[4 * 2112];    // per-wave P: chunk stride 264 elems
  int tid = threadIdx.x;
  int wave = tid >> 6, lane = tid & 63, quad = lane >> 4, l16 = lane & 15;
  int h = blockIdx.y, b = blockIdx.z;
  int kvh = h >> 2;

  // staging base pointers (qt-independent)
  const bf16* Kb[4];
  const bf16* Vb[4];
  {
    int r4 = lane >> 4, c16 = lane & 15;
    int r8 = lane >> 3, c8 = lane & 7;
#pragma unroll
    for (int u = 0; u < 4; u++) {
      int t = wave + 4 * u;
      int krow = 4 * t + r4;
      int kc = c16 ^ (krow & 7);
      Kb[u] = Km + (size_t)(b * S_ + krow) * (NKV_ * HD_) + kvh * HD_ + kc * 8;
      int vrow = 8 * t + r8;
      int vc = c8 ^ (vrow & 7);
      Vb[u] = VtG + (size_t)(kvh * HD_ + vrow) * T_ + b * S_ + vc * 8;
    }
  }

  for (int pass = 0; pass < 2; pass++) {
    int qt = pass ? ((S_ / 128 - 1) - (int)blockIdx.x) : (int)blockIdx.x;
    int q0 = qt * 128;

    bf16x8 aQ[2][4];
#pragma unroll
    for (int mt = 0; mt < 2; mt++) {
      int row = q0 + wave * 32 + mt * 16 + l16;
      const bf16* qb = Qm + (size_t)(b * S_ + row) * (NH_ * HD_) + h * HD_;
#pragma unroll
      for (int kt = 0; kt < 4; kt++)
        aQ[mt][kt] = *(const bf16x8*)(qb + kt * 32 + quad * 8);
    }

    float mcur[2][4], lcur[2][4];
    f32x4 O[2][8];
#pragma unroll
    for (int mt = 0; mt < 2; mt++)
#pragma unroll
      for (int r = 0; r < 4; r++) { mcur[mt][r] = -1e30f; lcur[mt][r] = 0.f; }
#pragma unroll
    for (int mt = 0; mt < 2; mt++)
#pragma unroll
      for (int n = 0; n < 8; n++) O[mt][n] = (f32x4){0.f, 0.f, 0.f, 0.f};

    for (int j0 = 0; j0 < q0 + 128; j0 += 64) {
      __syncthreads();
#pragma unroll
      for (int u = 0; u < 4; u++) {
        int t = wave + 4 * u;
        load_lds16(Kb[u] + (size_t)j0 * (NKV_ * HD_), (char*)Ks + t * 1024);
        load_lds16(Vb[u] + j0,                        (char*)Vt + t * 1024);
      }
      __syncthreads();

      f32x4 sc[2][4];
#pragma unroll
      for (int mt = 0; mt < 2; mt++)
#pragma unroll
        for (int nt = 0; nt < 4; nt++) sc[mt][nt] = (f32x4){0.f, 0.f, 0.f, 0.f};
#pragma unroll
      for (int kt = 0; kt < 4; kt++) {
        bf16x8 bk[4];
#pragma unroll
        for (int nt = 0; nt < 4; nt++) {
          int key = nt * 16 + l16;
          bk[nt] = *(const bf16x8*)((const char*)Ks + key * 256 + (((kt * 4 + quad) ^ (key & 7)) << 4));
        }
#pragma unroll
        for (int mt = 0; mt < 2; mt++)
#pragma unroll
          for (int nt = 0; nt < 4; nt++)
            sc[mt][nt] = __builtin_amdgcn_mfma_f32_16x16x32_bf16(aQ[mt][kt], bk[nt], sc[mt][nt], 0, 0, 0);
      }

#pragma unroll
      for (int mt = 0; mt < 2; mt++) {
        int rowb = q0 + wave * 32 + mt * 16 + quad * 4;
        float rmax[4] = {-1e30f, -1e30f, -1e30f, -1e30f};
#pragma unroll
        for (int nt = 0; nt < 4; nt++) {
          int col = j0 + nt * 16 + l16;
#pragma unroll
          for (int r = 0; r < 4; r++) {
            float v = sc[mt][nt][r] + ((col > rowb + r) ? -1e9f : 0.f);
            sc[mt][nt][r] = v;
            rmax[r] = fmaxf(rmax[r], v);
          }
        }
#pragma unroll
        for (int m = 1; m < 16; m <<= 1)
#pragma unroll
          for (int r = 0; r < 4; r++)
            rmax[r] = fmaxf(rmax[r], __shfl_xor(rmax[r], m));
        float alpha[4];
#pragma unroll
        for (int r = 0; r < 4; r++) {
          float mnew = fmaxf(mcur[mt][r], rmax[r]);
          alpha[r] = __expf(mcur[mt][r] - mnew);
          mcur[mt][r] = mnew;
        }
        float rsum[4] = {0.f, 0.f, 0.f, 0.f};
#pragma unroll
        for (int nt = 0; nt < 4; nt++)
#pragma unroll
          for (int r = 0; r < 4; r++) {
            float p = __expf(sc[mt][nt][r] - mcur[mt][r]);
            sc[mt][nt][r] = p;
            rsum[r] += p;
          }
#pragma unroll
        for (int m = 1; m < 16; m <<= 1)
#pragma unroll
          for (int r = 0; r < 4; r++)
            rsum[r] += __shfl_xor(rsum[r], m);
#pragma unroll
        for (int r = 0; r < 4; r++) lcur[mt][r] = lcur[mt][r] * alpha[r] + rsum[r];
#pragma unroll
        for (int n = 0; n < 8; n++)
#pragma unroll
          for (int r = 0; r < 4; r++) O[mt][n][r] *= alpha[r];
#pragma unroll
        for (int nt = 0; nt < 4; nt++) {
          int key = nt * 16 + l16;
#pragma unroll
          for (int r = 0; r < 4; r++)
            Ps[wave * 2112 + (key >> 3) * 264 + (mt * 16 + quad * 4 + r) * 8 + (key & 7)] = (bf16)sc[mt][nt][r];
        }
      }

#pragma unroll
      for (int kt = 0; kt < 2; kt++) {
        bf16x8 ap[2];
#pragma unroll
        for (int mt = 0; mt < 2; mt++)
          ap[mt] = *(const bf16x8*)&Ps[wave * 2112 + (kt * 4 + quad) * 264 + (mt * 16 + l16) * 8];
#pragma unroll
        for (int nt = 0; nt < 8; nt++) {
          int d = nt * 16 + l16;
          bf16x8 bv = *(const bf16x8*)((const char*)Vt + d * 128 + (((kt * 4 + quad) ^ (d & 7)) << 4));
#pragma unroll
          for (int mt = 0; mt < 2; mt++)
            O[mt][nt] = __builtin_amdgcn_mfma_f32_16x16x32_bf16(ap[mt], bv, O[mt][nt], 0, 0, 0);
        }
      }
    }

#pragma unroll
    for (int mt = 0; mt < 2; mt++)
#pragma unroll
      for (int nt = 0; nt < 8; nt++)
#pragma unroll
        for (int r = 0; r < 4; r++) {
          int row = q0 + wave * 32 + mt * 16 + quad * 4 + r;
          Cm[(size_t)(b * S_ + row) * (NH_ * HD_) + h * HD_ + nt * 16 + l16] =
              (bf16)(O[mt][nt][r] / lcur[mt][r]);
        }
  }
}

extern "C" void kernel_launch(void* const* d_in, const int* in_sizes, int n_in,
                              void* d_out, int out_size, void* d_ws, size_t ws_size,
                              hipStream_t stream) {
  const float* hidden = (const float*)d_in[0];
  const float* cosT   = (const float*)d_in[1];
  const float* sinT   = (const float*)d_in[2];
  const int*   q_qw = (const int*)d_in[4];
  const float* q_sc = (const float*)d_in[5];
  const int*   k_qw = (const int*)d_in[6];
  const float* k_sc = (const float*)d_in[7];
  const int*   v_qw = (const int*)d_in[8];
  const float* v_sc = (const float*)d_in[9];
  const int*   o_qw = (const int*)d_in[10];
  const float* o_sc = (const float*)d_in[11];

  const size_t MB = 1024 * 1024;
  char* ws = (char*)d_ws;
  bf16* Xb  = (bf16*)(ws);             // 32MB  hidden bf16; later reused as ctx
  bf16* Wb  = (bf16*)(ws + 32 * MB);   // 32MB  current dequantized weight
  bf16* Qm  = (bf16*)(ws + 64 * MB);   // 32MB  [T][4096]
  bf16* Km  = (bf16*)(ws + 96 * MB);   // 8MB   [T][1024]
  bf16* VtG = (bf16*)(ws + 104 * MB);  // 8MB   [1024][T]  (V transposed)
  bf16* Cm  = Xb;

  cvt_bf16_kernel<<<(T_ * HID_ / 4 + 255) / 256, 256, 0, stream>>>(hidden, Xb, T_ * HID_ / 4);

  const float scaling = 0.08838834764831845f;  // 1/sqrt(128)

  // Q projection + fused rope (scale folded)
  dequant_kernel<<<(4096 * 512 + 255) / 256, 256, 0, stream>>>(q_qw, q_sc, Wb, 4096, 4096);
  gemm_rope_kernel<<<dim3(32, 32), 256, 0, stream>>>(Xb, Wb, Qm, 4096, 4096, cosT, sinT, scaling);

  // K projection + fused rope
  dequant_kernel<<<(1024 * 512 + 255) / 256, 256, 0, stream>>>(k_qw, k_sc, Wb, 1024, 4096);
  gemm_rope_kernel<<<dim3(8, 32), 256, 0, stream>>>(Xb, Wb, Km, 1024, 4096, cosT, sinT, 1.0f);

  // V projection, written TRANSPOSED: V^T[1024][T] = Wv * X^T
  dequant_kernel<<<(1024 * 512 + 255) / 256, 256, 0, stream>>>(v_qw, v_sc, Wb, 1024, 4096);
  gemm_bt_kernel<<<dim3(32, 8), 256, 0, stream>>>(Wb, Xb, VtG, 4096, 4096, 0);

  // attention (paired q-tiles; writes Cm = Xb region)
  attn_kernel<<<dim3(8, NH_, B_), 256, 0, stream>>>(Qm, Km, VtG, Cm);

  // output projection -> fp32 d_out
  dequant_kernel<<<(4096 * 512 + 255) / 256, 256, 0, stream>>>(o_qw, o_sc, Wb, 4096, 4096);
  gemm_bt_kernel<<<dim3(32, 32), 256, 0, stream>>>(Cm, Wb, d_out, 4096, 4096, 1);
}

// Round 4
// 904.785 us; speedup vs baseline: 2.1941x; 1.1441x over previous
//
#include <hip/hip_runtime.h>
#include <hip/hip_bf16.h>

#define B_ 2
#define S_ 2048
#define HID_ 4096
#define NH_ 32
#define NKV_ 8
#define HD_ 128
#define T_ (B_*S_)

typedef __bf16 bf16;
typedef __bf16 bf16x8 __attribute__((ext_vector_type(8)));
typedef __bf16 bf16x4 __attribute__((ext_vector_type(4)));
typedef float f32x4 __attribute__((ext_vector_type(4)));

// async global->LDS, 16B per lane; LDS dest = base + lane*16 (wave-uniform base)
__device__ __forceinline__ void load_lds16(const void* g, void* l) {
  __builtin_amdgcn_global_load_lds((const __attribute__((address_space(1))) void*)g,
                                   (__attribute__((address_space(3))) void*)l, 16, 0, 0);
}

// DPP row_ror cross-lane (16-lane ring) — VALU-speed reduction, no LDS pipe
#define DPP_ROR(x, n) __int_as_float(__builtin_amdgcn_update_dpp( \
    __float_as_int(x), __float_as_int(x), 0x120 | (n), 0xf, 0xf, false))
__device__ __forceinline__ float red16_max(float x) {
  x = fmaxf(x, DPP_ROR(x, 1)); x = fmaxf(x, DPP_ROR(x, 2));
  x = fmaxf(x, DPP_ROR(x, 4)); x = fmaxf(x, DPP_ROR(x, 8));
  return x;
}
__device__ __forceinline__ float red16_sum(float x) {
  x += DPP_ROR(x, 1); x += DPP_ROR(x, 2);
  x += DPP_ROR(x, 4); x += DPP_ROR(x, 8);
  return x;
}

// ---------------- convert fp32 -> bf16 ----------------
__global__ __launch_bounds__(256) void cvt_bf16_kernel(const float* __restrict__ in,
                                                       bf16* __restrict__ out, int n4) {
  int idx = blockIdx.x * 256 + threadIdx.x;
  if (idx >= n4) return;
  float4 v = ((const float4*)in)[idx];
  bf16x4 o;
  o.x = (bf16)v.x; o.y = (bf16)v.y; o.z = (bf16)v.z; o.w = (bf16)v.w;
  ((bf16x4*)out)[idx] = o;
}

// ---------------- dequant int4(stored int32) -> bf16 ----------------
__global__ __launch_bounds__(256) void dequant_kernel(const int* __restrict__ qw,
                                                      const float* __restrict__ scale,
                                                      bf16* __restrict__ out,
                                                      int OD, int ID) {
  int idx = blockIdx.x * 256 + threadIdx.x;
  int perRow = ID >> 3;
  int total = OD * perRow;
  if (idx >= total) return;
  int o = idx / perRow;
  int ic = idx - o * perRow;
  float s = scale[o * (ID >> 7) + ((ic * 8) >> 7)];
  const int* q = qw + (size_t)o * ID + ic * 8;
  int4 q0 = *(const int4*)q;
  int4 q1 = *(const int4*)(q + 4);
  bf16x8 r;
  r[0] = (bf16)((q0.x - 8) * s);
  r[1] = (bf16)((q0.y - 8) * s);
  r[2] = (bf16)((q0.z - 8) * s);
  r[3] = (bf16)((q0.w - 8) * s);
  r[4] = (bf16)((q1.x - 8) * s);
  r[5] = (bf16)((q1.y - 8) * s);
  r[6] = (bf16)((q1.z - 8) * s);
  r[7] = (bf16)((q1.w - 8) * s);
  *(bf16x8*)(out + (size_t)o * ID + ic * 8) = r;
}

// ---------------- GEMM: C[M][N] = A[M][K] * B[N][K]^T (plain) ----------------
__global__ __launch_bounds__(256) void gemm_bt_kernel(const bf16* __restrict__ A,
                                                      const bf16* __restrict__ Bm,
                                                      void* __restrict__ Cout,
                                                      int N, int K, int c_fp32) {
  __shared__ bf16 As[8192];
  __shared__ bf16 Bs[8192];
  int tid = threadIdx.x;
  int wave = tid >> 6, lane = tid & 63, quad = lane >> 4, l16 = lane & 15;
  int m0 = blockIdx.y * 128, n0 = blockIdx.x * 128;
  int wm = (wave >> 1) * 64, wn = (wave & 1) * 64;

  int srow = lane >> 3;
  int schunk = (lane & 7) ^ (srow & 7);
  const bf16* Ab[4];
  const bf16* Bb[4];
#pragma unroll
  for (int u = 0; u < 4; u++) {
    int t = wave + 4 * u;
    Ab[u] = A  + (size_t)(m0 + 8 * t + srow) * K + schunk * 8;
    Bb[u] = Bm + (size_t)(n0 + 8 * t + srow) * K + schunk * 8;
  }

  f32x4 acc[4][4];
#pragma unroll
  for (int mt = 0; mt < 4; mt++)
#pragma unroll
    for (int nt = 0; nt < 4; nt++) acc[mt][nt] = (f32x4){0.f, 0.f, 0.f, 0.f};

  for (int k0 = 0; k0 < K; k0 += 64) {
    __syncthreads();
#pragma unroll
    for (int u = 0; u < 4; u++) {
      int t = wave + 4 * u;
      load_lds16(Ab[u] + k0, (char*)As + t * 1024);
      load_lds16(Bb[u] + k0, (char*)Bs + t * 1024);
    }
    __syncthreads();
#pragma unroll
    for (int kk = 0; kk < 2; kk++) {
      bf16x8 af[4], bfr[4];
#pragma unroll
      for (int mt = 0; mt < 4; mt++) {
        int r = wm + mt * 16 + l16;
        af[mt] = *(const bf16x8*)((const char*)As + r * 128 + (((kk * 4 + quad) ^ (r & 7)) << 4));
      }
#pragma unroll
      for (int nt = 0; nt < 4; nt++) {
        int r = wn + nt * 16 + l16;
        bfr[nt] = *(const bf16x8*)((const char*)Bs + r * 128 + (((kk * 4 + quad) ^ (r & 7)) << 4));
      }
#pragma unroll
      for (int mt = 0; mt < 4; mt++)
#pragma unroll
        for (int nt = 0; nt < 4; nt++)
          acc[mt][nt] = __builtin_amdgcn_mfma_f32_16x16x32_bf16(af[mt], bfr[nt], acc[mt][nt], 0, 0, 0);
    }
  }

#pragma unroll
  for (int mt = 0; mt < 4; mt++)
#pragma unroll
    for (int nt = 0; nt < 4; nt++)
#pragma unroll
      for (int r = 0; r < 4; r++) {
        int rr = m0 + wm + mt * 16 + quad * 4 + r;
        int cc = n0 + wn + nt * 16 + l16;
        if (c_fp32) ((float*)Cout)[(size_t)rr * N + cc] = acc[mt][nt][r];
        else        ((bf16*)Cout)[(size_t)rr * N + cc] = (bf16)acc[mt][nt][r];
      }
}

// ---------------- GEMM + fused RoPE epilogue (Q and K projections) ----------
__global__ __launch_bounds__(256) void gemm_rope_kernel(const bf16* __restrict__ A,
                                                        const bf16* __restrict__ Bm,
                                                        bf16* __restrict__ Out,
                                                        int N, int K,
                                                        const float* __restrict__ cosT,
                                                        const float* __restrict__ sinT,
                                                        float outscale) {
  __shared__ char smem[32768];
  bf16* As = (bf16*)smem;
  bf16* Bs = (bf16*)(smem + 16384);
  float* Ex = (float*)smem;   // 256*17 floats, aliases As/Bs after main loop
  int tid = threadIdx.x;
  int wave = tid >> 6, lane = tid & 63, quad = lane >> 4, l16 = lane & 15;
  int m0 = blockIdx.y * 128, n0 = blockIdx.x * 128;
  int wm = (wave >> 1) * 64, wn = (wave & 1) * 64;

  int srow = lane >> 3;
  int schunk = (lane & 7) ^ (srow & 7);
  const bf16* Ab[4];
  const bf16* Bb[4];
#pragma unroll
  for (int u = 0; u < 4; u++) {
    int t = wave + 4 * u;
    Ab[u] = A  + (size_t)(m0 + 8 * t + srow) * K + schunk * 8;
    Bb[u] = Bm + (size_t)(n0 + 8 * t + srow) * K + schunk * 8;
  }

  f32x4 acc[4][4];
#pragma unroll
  for (int mt = 0; mt < 4; mt++)
#pragma unroll
    for (int nt = 0; nt < 4; nt++) acc[mt][nt] = (f32x4){0.f, 0.f, 0.f, 0.f};

  for (int k0 = 0; k0 < K; k0 += 64) {
    __syncthreads();
#pragma unroll
    for (int u = 0; u < 4; u++) {
      int t = wave + 4 * u;
      load_lds16(Ab[u] + k0, (char*)As + t * 1024);
      load_lds16(Bb[u] + k0, (char*)Bs + t * 1024);
    }
    __syncthreads();
#pragma unroll
    for (int kk = 0; kk < 2; kk++) {
      bf16x8 af[4], bfr[4];
#pragma unroll
      for (int mt = 0; mt < 4; mt++) {
        int r = wm + mt * 16 + l16;
        af[mt] = *(const bf16x8*)((const char*)As + r * 128 + (((kk * 4 + quad) ^ (r & 7)) << 4));
      }
#pragma unroll
      for (int nt = 0; nt < 4; nt++) {
        int r = wn + nt * 16 + l16;
        bfr[nt] = *(const bf16x8*)((const char*)Bs + r * 128 + (((kk * 4 + quad) ^ (r & 7)) << 4));
      }
#pragma unroll
      for (int mt = 0; mt < 4; mt++)
#pragma unroll
        for (int nt = 0; nt < 4; nt++)
          acc[mt][nt] = __builtin_amdgcn_mfma_f32_16x16x32_bf16(af[mt], bfr[nt], acc[mt][nt], 0, 0, 0);
    }
  }

  int myb = tid * 17;
  int pb = (tid ^ 64) * 17;    // partner: other 64-col half, same lane/regs
#pragma unroll
  for (int mt = 0; mt < 4; mt++) {
    __syncthreads();
#pragma unroll
    for (int nt = 0; nt < 4; nt++)
#pragma unroll
      for (int r = 0; r < 4; r++)
        Ex[myb + nt * 4 + r] = acc[mt][nt][r];
    __syncthreads();
    int rowb = m0 + wm + mt * 16 + quad * 4;
#pragma unroll
    for (int nt = 0; nt < 4; nt++) {
      int cc = n0 + wn + nt * 16 + l16;
      int d = cc & 127;
#pragma unroll
      for (int r = 0; r < 4; r++) {
        int row = rowb + r;
        int t = row & (S_ - 1);
        float self = acc[mt][nt][r];
        float other = Ex[pb + nt * 4 + r];
        float c = cosT[t * 128 + d], s = sinT[t * 128 + d];
        float o = (d < 64) ? (self * c - other * s) : (self * c + other * s);
        Out[(size_t)row * N + cc] = (bf16)(o * outscale);
      }
    }
  }
}

// ---------------- fused causal GQA attention -----------------------------
// grid (8, NH, B), 512 threads = 8 waves; wave owns 16 Q rows; paired q-tiles
// (qt, 15-qt) -> uniform 34 j-iterations. K double-buffered + pipelined,
// V staged behind the QK^T/softmax phase. DPP reductions, exp2-domain softmax
// (Q pre-scaled by 1/sqrt(d)*log2(e) in rope epilogue).
__global__ __launch_bounds__(512, 4) void attn_kernel(const bf16* __restrict__ Qm,
                                                      const bf16* __restrict__ Km,
                                                      const bf16* __restrict__ VtG,
                                                      bf16* __restrict__ Cm) {
  __shared__ char sK[32768];   // 2 x 16KB: addr(key,dc16)=key*256 + ((dc^(key&7))<<4)
  __shared__ char sV[16384];   // addr(d,kc8)=d*128 + ((kc^(d&7))<<4)
  __shared__ char sP[16384];   // 8 waves x 2KB: addr(m,kc8)=m*128 + ((kc^(m&7))<<4)
  int tid = threadIdx.x;
  int wave = tid >> 6, lane = tid & 63, quad = lane >> 4, l16 = lane & 15;
  int h = blockIdx.y, b = blockIdx.z;
  int kvh = h >> 2;

  // staging pointers (qt-independent); each wave stages 2x1KB of K and of V
  const bf16* Kb[2];
  const bf16* Vb[2];
  {
    int r4 = lane >> 4, c16 = lane & 15;
    int r8 = lane >> 3, c8 = lane & 7;
#pragma unroll
    for (int u = 0; u < 2; u++) {
      int t = wave * 2 + u;
      int key = 4 * t + r4;
      int kc = c16 ^ (key & 7);
      Kb[u] = Km + (size_t)(b * S_ + key) * (NKV_ * HD_) + kvh * HD_ + kc * 8;
      int d = 8 * t + r8;
      int vc = c8 ^ (d & 7);
      Vb[u] = VtG + (size_t)(kvh * HD_ + d) * T_ + (size_t)b * S_ + vc * 8;
    }
  }

  for (int pass = 0; pass < 2; pass++) {
    int qt = pass ? ((S_ / 128 - 1) - (int)blockIdx.x) : (int)blockIdx.x;
    int q0 = qt * 128;
    int jend = q0 + 128;

    // pre-stage K tile j0=0 into buffer 0 (safe: pass N-1 readers are past
    // their last barrier before any wave gets here)
#pragma unroll
    for (int u = 0; u < 2; u++)
      load_lds16(Kb[u], sK + (wave * 2 + u) * 1024);

    // Q fragments: A[m=l16][k=quad*8+j]
    bf16x8 aQ[4];
    {
      int row = q0 + wave * 16 + l16;
      const bf16* qb = Qm + (size_t)(b * S_ + row) * (NH_ * HD_) + h * HD_;
#pragma unroll
      for (int kt = 0; kt < 4; kt++)
        aQ[kt] = *(const bf16x8*)(qb + kt * 32 + quad * 8);
    }

    float mcur[4], lcur[4];
    f32x4 O[8];
#pragma unroll
    for (int r = 0; r < 4; r++) { mcur[r] = -1e30f; lcur[r] = 0.f; }
#pragma unroll
    for (int n = 0; n < 8; n++) O[n] = (f32x4){0.f, 0.f, 0.f, 0.f};

    for (int j0 = 0; j0 < jend; j0 += 64) {
      int cur = (j0 >> 6) & 1;
      __syncthreads();   // K(cur) staged (issued one full iteration ago)
      // issue next K tile + this iteration's V tile (both land during compute)
      if (j0 + 64 < jend) {
#pragma unroll
        for (int u = 0; u < 2; u++)
          load_lds16(Kb[u] + (size_t)(j0 + 64) * (NKV_ * HD_),
                     sK + (1 - cur) * 16384 + (wave * 2 + u) * 1024);
      }
#pragma unroll
      for (int u = 0; u < 2; u++)
        load_lds16(Vb[u] + j0, sV + (wave * 2 + u) * 1024);

      // QK^T: 16 rows x 64 keys per wave
      const char* Kc = sK + cur * 16384;
      f32x4 sc[4];
#pragma unroll
      for (int nt = 0; nt < 4; nt++) sc[nt] = (f32x4){0.f, 0.f, 0.f, 0.f};
#pragma unroll
      for (int kt = 0; kt < 4; kt++) {
        bf16x8 bk[4];
#pragma unroll
        for (int nt = 0; nt < 4; nt++) {
          int key = nt * 16 + l16;
          bk[nt] = *(const bf16x8*)(Kc + key * 256 + (((kt * 4 + quad) ^ (key & 7)) << 4));
        }
#pragma unroll
        for (int nt = 0; nt < 4; nt++)
          sc[nt] = __builtin_amdgcn_mfma_f32_16x16x32_bf16(aQ[kt], bk[nt], sc[nt], 0, 0, 0);
      }

      // causal mask (wave-uniform skip for fully-visible tiles)
      int rowb = q0 + wave * 16 + quad * 4;
      if (j0 + 63 > q0 + wave * 16) {
#pragma unroll
        for (int nt = 0; nt < 4; nt++) {
          int col = j0 + nt * 16 + l16;
#pragma unroll
          for (int r = 0; r < 4; r++)
            if (col > rowb + r) sc[nt][r] = -1e9f;
        }
      }

      // online softmax (log2 domain; DPP reductions)
      float rmax[4], alpha[4], rsum[4];
#pragma unroll
      for (int r = 0; r < 4; r++) {
        float v = fmaxf(fmaxf(sc[0][r], sc[1][r]), fmaxf(sc[2][r], sc[3][r]));
        rmax[r] = red16_max(v);
        float mnew = fmaxf(mcur[r], rmax[r]);
        alpha[r] = exp2f(mcur[r] - mnew);
        mcur[r] = mnew;
      }
#pragma unroll
      for (int nt = 0; nt < 4; nt++)
#pragma unroll
        for (int r = 0; r < 4; r++)
          sc[nt][r] = exp2f(sc[nt][r] - mcur[r]);
#pragma unroll
      for (int r = 0; r < 4; r++) {
        float s = (sc[0][r] + sc[1][r]) + (sc[2][r] + sc[3][r]);
        rsum[r] = red16_sum(s);
        lcur[r] = lcur[r] * alpha[r] + rsum[r];
      }
#pragma unroll
      for (int n = 0; n < 8; n++)
#pragma unroll
        for (int r = 0; r < 4; r++) O[n][r] *= alpha[r];

      // P -> LDS (C-layout -> A-frag layout), wave-private region
      char* Pw = sP + wave * 2048;
#pragma unroll
      for (int nt = 0; nt < 4; nt++) {
        int key = nt * 16 + l16;
#pragma unroll
        for (int r = 0; r < 4; r++) {
          int m = quad * 4 + r;
          *(bf16*)(Pw + m * 128 + (((key >> 3) ^ (m & 7)) << 4) + (key & 7) * 2) =
              (bf16)sc[nt][r];
        }
      }

      __syncthreads();   // V(cur) staged (landed during QK^T+softmax); P visible intra-wave

      // ctx += P * V
#pragma unroll
      for (int kt = 0; kt < 2; kt++) {
        bf16x8 ap = *(const bf16x8*)(Pw + l16 * 128 + (((kt * 4 + quad) ^ (l16 & 7)) << 4));
#pragma unroll
        for (int nt = 0; nt < 8; nt++) {
          int d = nt * 16 + l16;
          bf16x8 bv = *(const bf16x8*)(sV + d * 128 + (((kt * 4 + quad) ^ (d & 7)) << 4));
          O[nt] = __builtin_amdgcn_mfma_f32_16x16x32_bf16(ap, bv, O[nt], 0, 0, 0);
        }
      }
    }

    // epilogue
#pragma unroll
    for (int nt = 0; nt < 8; nt++)
#pragma unroll
      for (int r = 0; r < 4; r++) {
        int row = q0 + wave * 16 + quad * 4 + r;
        Cm[(size_t)(b * S_ + row) * (NH_ * HD_) + h * HD_ + nt * 16 + l16] =
            (bf16)(O[nt][r] / lcur[r]);
      }
  }
}

extern "C" void kernel_launch(void* const* d_in, const int* in_sizes, int n_in,
                              void* d_out, int out_size, void* d_ws, size_t ws_size,
                              hipStream_t stream) {
  const float* hidden = (const float*)d_in[0];
  const float* cosT   = (const float*)d_in[1];
  const float* sinT   = (const float*)d_in[2];
  const int*   q_qw = (const int*)d_in[4];
  const float* q_sc = (const float*)d_in[5];
  const int*   k_qw = (const int*)d_in[6];
  const float* k_sc = (const float*)d_in[7];
  const int*   v_qw = (const int*)d_in[8];
  const float* v_sc = (const float*)d_in[9];
  const int*   o_qw = (const int*)d_in[10];
  const float* o_sc = (const float*)d_in[11];

  const size_t MB = 1024 * 1024;
  char* ws = (char*)d_ws;
  bf16* Xb  = (bf16*)(ws);             // 32MB  hidden bf16; later reused as ctx
  bf16* Wb  = (bf16*)(ws + 32 * MB);   // 32MB  current dequantized weight
  bf16* Qm  = (bf16*)(ws + 64 * MB);   // 32MB  [T][4096]
  bf16* Km  = (bf16*)(ws + 96 * MB);   // 8MB   [T][1024]
  bf16* VtG = (bf16*)(ws + 104 * MB);  // 8MB   [1024][T]  (V transposed)
  bf16* Cm  = Xb;

  cvt_bf16_kernel<<<(T_ * HID_ / 4 + 255) / 256, 256, 0, stream>>>(hidden, Xb, T_ * HID_ / 4);

  // Q pre-scale: 1/sqrt(128) * log2(e)  (softmax runs in exp2 domain)
  const float qscale = (float)(0.08838834764831845 * 1.4426950408889634);

  // Q projection + fused rope
  dequant_kernel<<<(4096 * 512 + 255) / 256, 256, 0, stream>>>(q_qw, q_sc, Wb, 4096, 4096);
  gemm_rope_kernel<<<dim3(32, 32), 256, 0, stream>>>(Xb, Wb, Qm, 4096, 4096, cosT, sinT, qscale);

  // K projection + fused rope
  dequant_kernel<<<(1024 * 512 + 255) / 256, 256, 0, stream>>>(k_qw, k_sc, Wb, 1024, 4096);
  gemm_rope_kernel<<<dim3(8, 32), 256, 0, stream>>>(Xb, Wb, Km, 1024, 4096, cosT, sinT, 1.0f);

  // V projection, written TRANSPOSED: V^T[1024][T] = Wv * X^T
  dequant_kernel<<<(1024 * 512 + 255) / 256, 256, 0, stream>>>(v_qw, v_sc, Wb, 1024, 4096);
  gemm_bt_kernel<<<dim3(32, 8), 256, 0, stream>>>(Wb, Xb, VtG, 4096, 4096, 0);

  // attention (8 waves/block, paired q-tiles; writes Cm = Xb region)
  attn_kernel<<<dim3(8, NH_, B_), 512, 0, stream>>>(Qm, Km, VtG, Cm);

  // output projection -> fp32 d_out
  dequant_kernel<<<(4096 * 512 + 255) / 256, 256, 0, stream>>>(o_qw, o_sc, Wb, 4096, 4096);
  gemm_bt_kernel<<<dim3(32, 32), 256, 0, stream>>>(Cm, Wb, d_out, 4096, 4096, 1);
}